// Round 6
// baseline (88.963 us; speedup 1.0000x reference)
//
#include <hip/hip_runtime.h>

// Problem constants (B,S,H) = (8,2048,4096), N_POOL=6, N_LAYERS=32
constexpr int kS     = 2048;
constexpr int kH     = 4096;
constexpr int kNPOOL = 6;
constexpr int kNLAY  = 32;
constexpr int kNK    = 7;     // N_POOL + 1
constexpr int kRPIN  = 10240; // rows of x read CACHED (160 MiB pinned in 256 MiB L3)

// Native vector type: __builtin_nontemporal_* rejects HIP's float4 class.
typedef float f32x4 __attribute__((ext_vector_type(4)));

// One block per (b,s) row, 16384 blocks x 256 threads.
// Cache partitioning: rows < kRPIN load CACHED (pinned L3 set, survives across
// graph replays because every other stream is nontemporal/evict-first);
// rows >= kRPIN load NT (stream from HBM without polluting the pinned set).
// All copy-path stores NT (268 MB write is mandatory HBM traffic; don't let
// it allocate and evict the pinned reads).
__global__ __launch_bounds__(256) void fused_gate_copy(
    const float* __restrict__ x,
    const float* __restrict__ gate_w,
    const float* __restrict__ gate_b,
    const float* __restrict__ pool,
    const int*   __restrict__ layer_idx_p,
    float*       __restrict__ out)
{
    const int row  = blockIdx.x;          // row = b*S + s
    const int s    = row & (kS - 1);
    const int tid  = threadIdx.x;
    const size_t base = (size_t)row * kH;

    if (s != kS - 1) {
        const f32x4* __restrict__ srcv = reinterpret_cast<const f32x4*>(x + base);
        f32x4*       __restrict__ dstv = reinterpret_cast<f32x4*>(out + base);
        f32x4 v0, v1, v2, v3;
        if (row < kRPIN) {
            // pinned region: cached loads
            v0 = srcv[tid + 0 * 256];
            v1 = srcv[tid + 1 * 256];
            v2 = srcv[tid + 2 * 256];
            v3 = srcv[tid + 3 * 256];
        } else {
            // streaming region: NT loads (evict-first, don't pollute pin)
            v0 = __builtin_nontemporal_load(srcv + (tid + 0 * 256));
            v1 = __builtin_nontemporal_load(srcv + (tid + 1 * 256));
            v2 = __builtin_nontemporal_load(srcv + (tid + 2 * 256));
            v3 = __builtin_nontemporal_load(srcv + (tid + 3 * 256));
        }
        __builtin_nontemporal_store(v0, dstv + (tid + 0 * 256));
        __builtin_nontemporal_store(v1, dstv + (tid + 1 * 256));
        __builtin_nontemporal_store(v2, dstv + (tid + 2 * 256));
        __builtin_nontemporal_store(v3, dstv + (tid + 3 * 256));
        return;
    }

    // ---- gate path (8 blocks of 16384) ----
    const float4* __restrict__ src = reinterpret_cast<const float4*>(x + base);
    float4*       __restrict__ dst = reinterpret_cast<float4*>(out + base);

    const int b = row >> 11;              // row / S
    const int L = *layer_idx_p;

    // tok = x[b, S-1, :]
    float4 tokv[4];
    #pragma unroll
    for (int i = 0; i < 4; ++i) tokv[i] = src[tid + i * 256];

    // score[k] = sum_h tok[h] * gate_w[k][h]
    float acc[kNK];
    #pragma unroll
    for (int k = 0; k < kNK; ++k) acc[k] = 0.0f;

    #pragma unroll
    for (int k = 0; k < kNK; ++k) {
        const float4* wv = reinterpret_cast<const float4*>(gate_w + (size_t)k * kH);
        #pragma unroll
        for (int i = 0; i < 4; ++i) {
            const float4 w = wv[tid + i * 256];
            const float4 t = tokv[i];
            acc[k] += t.x * w.x + t.y * w.y + t.z * w.z + t.w * w.w;
        }
    }

    // 64-lane wave reduction
    #pragma unroll
    for (int k = 0; k < kNK; ++k) {
        float v = acc[k];
        #pragma unroll
        for (int off = 32; off > 0; off >>= 1)
            v += __shfl_down(v, off, 64);
        acc[k] = v;
    }

    // cross-wave reduction via LDS (4 waves)
    __shared__ float red[4][kNK];
    const int lane = tid & 63;
    const int wave = tid >> 6;
    if (lane == 0) {
        #pragma unroll
        for (int k = 0; k < kNK; ++k) red[wave][k] = acc[k];
    }
    __syncthreads();

    float score[kNK];
    #pragma unroll
    for (int k = 0; k < kNK; ++k)
        score[k] = red[0][k] + red[1][k] + red[2][k] + red[3][k] + gate_b[k];

    // softmax over 7 (redundant per thread)
    float m = score[0];
    #pragma unroll
    for (int k = 1; k < kNK; ++k) m = fmaxf(m, score[k]);
    float p[kNK];
    float sum = 0.0f;
    #pragma unroll
    for (int k = 0; k < kNK; ++k) { p[k] = expf(score[k] - m); sum += p[k]; }
    const float inv = 1.0f / sum;
    #pragma unroll
    for (int k = 0; k < kNK; ++k) p[k] *= inv;

    // new_vec = sum_{k<6} p[k]*pool[b,k,L,:] + p[6]*tok
    const size_t poolb = ((size_t)b * kNPOOL) * (size_t)(kNLAY * kH) + (size_t)L * kH;
    #pragma unroll
    for (int i = 0; i < 4; ++i) {
        const int v = tid + i * 256;
        const float4 t = tokv[i];
        float4 o;
        o.x = p[kNK - 1] * t.x;
        o.y = p[kNK - 1] * t.y;
        o.z = p[kNK - 1] * t.z;
        o.w = p[kNK - 1] * t.w;
        #pragma unroll
        for (int k = 0; k < kNPOOL; ++k) {
            const float4* pv = reinterpret_cast<const float4*>(
                pool + poolb + (size_t)k * (size_t)(kNLAY * kH));
            const float4 q = pv[v];
            o.x += p[k] * q.x;
            o.y += p[k] * q.y;
            o.z += p[k] * q.z;
            o.w += p[k] * q.w;
        }
        dst[v] = o;
    }
}

extern "C" void kernel_launch(void* const* d_in, const int* in_sizes, int n_in,
                              void* d_out, int out_size, void* d_ws, size_t ws_size,
                              hipStream_t stream) {
    const float* x      = (const float*)d_in[0];   // (8, 2048, 4096) f32
    const float* gate_w = (const float*)d_in[1];   // (7, 4096) f32
    const float* gate_b = (const float*)d_in[2];   // (7,) f32
    const float* pool   = (const float*)d_in[3];   // (8, 6, 32, 4096) f32
    const int*   lidx   = (const int*)d_in[4];     // scalar int
    float*       out    = (float*)d_out;           // (8, 2048, 4096) f32

    const int rows = out_size / kH;                // B*S = 16384
    fused_gate_copy<<<rows, 256, 0, stream>>>(x, gate_w, gate_b, pool, lidx, out);
}

// Round 7
// 86.748 us; speedup vs baseline: 1.0255x; 1.0255x over previous
//
#include <hip/hip_runtime.h>

// Problem constants (B,S,H) = (8,2048,4096), N_POOL=6, N_LAYERS=32
constexpr int kS     = 2048;
constexpr int kH     = 4096;
constexpr int kNPOOL = 6;
constexpr int kNLAY  = 32;
constexpr int kNK    = 7;    // N_POOL + 1

// Native vector type (HIP's float4 class is rejected by builtins/asm tuples).
typedef float f32x4 __attribute__((ext_vector_type(4)));

// Fully-bypassing streaming store: system-scope (sc0 sc1) + non-temporal (nt).
// Goal: out's 268 MB write stream must not allocate anywhere (L2 or MALL),
// leaving the 256 MiB Infinity Cache exclusively for x's read stream, which
// fits exactly -> cross-replay residency.
__device__ __forceinline__ void stream_store(f32x4* addr, f32x4 v) {
    asm volatile("global_store_dwordx4 %0, %1, off sc0 sc1 nt"
                 :
                 : "v"(addr), "v"(v)
                 : "memory");
}

// R5 structure (best measured): one block per (b,s) row, 16384 blocks x 256
// threads. Copy path: CACHED loads + bypassing streaming stores.
__global__ __launch_bounds__(256) void fused_gate_copy(
    const float* __restrict__ x,
    const float* __restrict__ gate_w,
    const float* __restrict__ gate_b,
    const float* __restrict__ pool,
    const int*   __restrict__ layer_idx_p,
    float*       __restrict__ out)
{
    const int row  = blockIdx.x;          // row = b*S + s
    const int s    = row & (kS - 1);
    const int tid  = threadIdx.x;
    const size_t base = (size_t)row * kH;

    if (s != kS - 1) {
        const f32x4* __restrict__ srcv = reinterpret_cast<const f32x4*>(x + base);
        f32x4*       __restrict__ dstv = reinterpret_cast<f32x4*>(out + base);
        const f32x4 v0 = srcv[tid + 0 * 256];
        const f32x4 v1 = srcv[tid + 1 * 256];
        const f32x4 v2 = srcv[tid + 2 * 256];
        const f32x4 v3 = srcv[tid + 3 * 256];
        stream_store(dstv + (tid + 0 * 256), v0);
        stream_store(dstv + (tid + 1 * 256), v1);
        stream_store(dstv + (tid + 2 * 256), v2);
        stream_store(dstv + (tid + 3 * 256), v3);
        return;
    }

    // ---- gate path (8 blocks of 16384) ----
    const float4* __restrict__ src = reinterpret_cast<const float4*>(x + base);
    float4*       __restrict__ dst = reinterpret_cast<float4*>(out + base);

    const int b = row >> 11;              // row / S
    const int L = *layer_idx_p;

    // tok = x[b, S-1, :]
    float4 tokv[4];
    #pragma unroll
    for (int i = 0; i < 4; ++i) tokv[i] = src[tid + i * 256];

    // score[k] = sum_h tok[h] * gate_w[k][h]
    float acc[kNK];
    #pragma unroll
    for (int k = 0; k < kNK; ++k) acc[k] = 0.0f;

    #pragma unroll
    for (int k = 0; k < kNK; ++k) {
        const float4* wv = reinterpret_cast<const float4*>(gate_w + (size_t)k * kH);
        #pragma unroll
        for (int i = 0; i < 4; ++i) {
            const float4 w = wv[tid + i * 256];
            const float4 t = tokv[i];
            acc[k] += t.x * w.x + t.y * w.y + t.z * w.z + t.w * w.w;
        }
    }

    // 64-lane wave reduction
    #pragma unroll
    for (int k = 0; k < kNK; ++k) {
        float v = acc[k];
        #pragma unroll
        for (int off = 32; off > 0; off >>= 1)
            v += __shfl_down(v, off, 64);
        acc[k] = v;
    }

    // cross-wave reduction via LDS (4 waves)
    __shared__ float red[4][kNK];
    const int lane = tid & 63;
    const int wave = tid >> 6;
    if (lane == 0) {
        #pragma unroll
        for (int k = 0; k < kNK; ++k) red[wave][k] = acc[k];
    }
    __syncthreads();

    float score[kNK];
    #pragma unroll
    for (int k = 0; k < kNK; ++k)
        score[k] = red[0][k] + red[1][k] + red[2][k] + red[3][k] + gate_b[k];

    // softmax over 7 (redundant per thread)
    float m = score[0];
    #pragma unroll
    for (int k = 1; k < kNK; ++k) m = fmaxf(m, score[k]);
    float p[kNK];
    float sum = 0.0f;
    #pragma unroll
    for (int k = 0; k < kNK; ++k) { p[k] = expf(score[k] - m); sum += p[k]; }
    const float inv = 1.0f / sum;
    #pragma unroll
    for (int k = 0; k < kNK; ++k) p[k] *= inv;

    // new_vec = sum_{k<6} p[k]*pool[b,k,L,:] + p[6]*tok
    const size_t poolb = ((size_t)b * kNPOOL) * (size_t)(kNLAY * kH) + (size_t)L * kH;
    #pragma unroll
    for (int i = 0; i < 4; ++i) {
        const int v = tid + i * 256;
        const float4 t = tokv[i];
        float4 o;
        o.x = p[kNK - 1] * t.x;
        o.y = p[kNK - 1] * t.y;
        o.z = p[kNK - 1] * t.z;
        o.w = p[kNK - 1] * t.w;
        #pragma unroll
        for (int k = 0; k < kNPOOL; ++k) {
            const float4* pv = reinterpret_cast<const float4*>(
                pool + poolb + (size_t)k * (size_t)(kNLAY * kH));
            const float4 q = pv[v];
            o.x += p[k] * q.x;
            o.y += p[k] * q.y;
            o.z += p[k] * q.z;
            o.w += p[k] * q.w;
        }
        dst[v] = o;
    }
}

extern "C" void kernel_launch(void* const* d_in, const int* in_sizes, int n_in,
                              void* d_out, int out_size, void* d_ws, size_t ws_size,
                              hipStream_t stream) {
    const float* x      = (const float*)d_in[0];   // (8, 2048, 4096) f32
    const float* gate_w = (const float*)d_in[1];   // (7, 4096) f32
    const float* gate_b = (const float*)d_in[2];   // (7,) f32
    const float* pool   = (const float*)d_in[3];   // (8, 6, 32, 4096) f32
    const int*   lidx   = (const int*)d_in[4];     // scalar int
    float*       out    = (float*)d_out;           // (8, 2048, 4096) f32

    const int rows = out_size / kH;                // B*S = 16384
    fused_gate_copy<<<rows, 256, 0, stream>>>(x, gate_w, gate_b, pool, lidx, out);
}

// Round 8
// 83.729 us; speedup vs baseline: 1.0625x; 1.0361x over previous
//
#include <hip/hip_runtime.h>

// Problem constants (B,S,H) = (8,2048,4096), N_POOL=6, N_LAYERS=32
constexpr int kS     = 2048;
constexpr int kH     = 4096;
constexpr int kNPOOL = 6;
constexpr int kNLAY  = 32;
constexpr int kNK    = 7;    // N_POOL + 1

typedef float f32x4 __attribute__((ext_vector_type(4)));

// 8192 blocks x 256 threads; block bi owns rows {2bi, 2bi+1} = 2048
// contiguous float4. Common path: 8 cached loads (deep MLP), 8 NT stores.
// Gate rows are odd (s = S-1) -> always the SECOND row of a pair, and its
// 4 loaded vectors double as tok.
__global__ __launch_bounds__(256) void fused_gate_copy(
    const float* __restrict__ x,
    const float* __restrict__ gate_w,
    const float* __restrict__ gate_b,
    const float* __restrict__ pool,
    const int*   __restrict__ layer_idx_p,
    float*       __restrict__ out)
{
    const int bi   = blockIdx.x;
    const int tid  = threadIdx.x;
    const int row1 = 2 * bi + 1;
    const size_t base = (size_t)(2 * bi) * kH;    // start of row pair

    const f32x4* __restrict__ srcv = reinterpret_cast<const f32x4*>(x + base);
    f32x4*       __restrict__ dstv = reinterpret_cast<f32x4*>(out + base);

    // 8 cached loads in flight (rows 2bi and 2bi+1)
    f32x4 v0 = srcv[tid + 0 * 256];
    f32x4 v1 = srcv[tid + 1 * 256];
    f32x4 v2 = srcv[tid + 2 * 256];
    f32x4 v3 = srcv[tid + 3 * 256];
    f32x4 v4 = srcv[tid + 4 * 256];
    f32x4 v5 = srcv[tid + 5 * 256];
    f32x4 v6 = srcv[tid + 6 * 256];
    f32x4 v7 = srcv[tid + 7 * 256];

    if ((row1 & (kS - 1)) != kS - 1) {
        // pure copy pair: 8 NT stores
        __builtin_nontemporal_store(v0, dstv + (tid + 0 * 256));
        __builtin_nontemporal_store(v1, dstv + (tid + 1 * 256));
        __builtin_nontemporal_store(v2, dstv + (tid + 2 * 256));
        __builtin_nontemporal_store(v3, dstv + (tid + 3 * 256));
        __builtin_nontemporal_store(v4, dstv + (tid + 4 * 256));
        __builtin_nontemporal_store(v5, dstv + (tid + 5 * 256));
        __builtin_nontemporal_store(v6, dstv + (tid + 6 * 256));
        __builtin_nontemporal_store(v7, dstv + (tid + 7 * 256));
        return;
    }

    // row0 is a plain copy row; row1 is the gate row, tok = {v4..v7}
    __builtin_nontemporal_store(v0, dstv + (tid + 0 * 256));
    __builtin_nontemporal_store(v1, dstv + (tid + 1 * 256));
    __builtin_nontemporal_store(v2, dstv + (tid + 2 * 256));
    __builtin_nontemporal_store(v3, dstv + (tid + 3 * 256));

    const int b = row1 >> 11;             // row1 / S
    const int L = *layer_idx_p;

    f32x4 tokv[4] = {v4, v5, v6, v7};

    // score[k] = sum_h tok[h] * gate_w[k][h]
    float acc[kNK];
    #pragma unroll
    for (int k = 0; k < kNK; ++k) acc[k] = 0.0f;

    #pragma unroll
    for (int k = 0; k < kNK; ++k) {
        const f32x4* wv = reinterpret_cast<const f32x4*>(gate_w + (size_t)k * kH);
        #pragma unroll
        for (int i = 0; i < 4; ++i) {
            const f32x4 r = tokv[i] * wv[tid + i * 256];
            acc[k] += r.x + r.y + r.z + r.w;
        }
    }

    // 64-lane wave reduction
    #pragma unroll
    for (int k = 0; k < kNK; ++k) {
        float v = acc[k];
        #pragma unroll
        for (int off = 32; off > 0; off >>= 1)
            v += __shfl_down(v, off, 64);
        acc[k] = v;
    }

    // cross-wave reduction via LDS (4 waves)
    __shared__ float red[4][kNK];
    const int lane = tid & 63;
    const int wave = tid >> 6;
    if (lane == 0) {
        #pragma unroll
        for (int k = 0; k < kNK; ++k) red[wave][k] = acc[k];
    }
    __syncthreads();

    float score[kNK];
    #pragma unroll
    for (int k = 0; k < kNK; ++k)
        score[k] = red[0][k] + red[1][k] + red[2][k] + red[3][k] + gate_b[k];

    // softmax over 7 (redundant per thread)
    float m = score[0];
    #pragma unroll
    for (int k = 1; k < kNK; ++k) m = fmaxf(m, score[k]);
    float p[kNK];
    float sum = 0.0f;
    #pragma unroll
    for (int k = 0; k < kNK; ++k) { p[k] = expf(score[k] - m); sum += p[k]; }
    const float inv = 1.0f / sum;
    #pragma unroll
    for (int k = 0; k < kNK; ++k) p[k] *= inv;

    // new_vec = sum_{k<6} p[k]*pool[b,k,L,:] + p[6]*tok
    const size_t poolb = ((size_t)b * kNPOOL) * (size_t)(kNLAY * kH) + (size_t)L * kH;
    #pragma unroll
    for (int i = 0; i < 4; ++i) {
        const int v = tid + (4 + i) * 256;      // row1 slot in the pair
        f32x4 o = p[kNK - 1] * tokv[i];
        #pragma unroll
        for (int k = 0; k < kNPOOL; ++k) {
            const f32x4* pv = reinterpret_cast<const f32x4*>(
                pool + poolb + (size_t)k * (size_t)(kNLAY * kH));
            o += p[k] * pv[tid + i * 256];
        }
        dstv[v] = o;
    }
}

extern "C" void kernel_launch(void* const* d_in, const int* in_sizes, int n_in,
                              void* d_out, int out_size, void* d_ws, size_t ws_size,
                              hipStream_t stream) {
    const float* x      = (const float*)d_in[0];   // (8, 2048, 4096) f32
    const float* gate_w = (const float*)d_in[1];   // (7, 4096) f32
    const float* gate_b = (const float*)d_in[2];   // (7,) f32
    const float* pool   = (const float*)d_in[3];   // (8, 6, 32, 4096) f32
    const int*   lidx   = (const int*)d_in[4];     // scalar int
    float*       out    = (float*)d_out;           // (8, 2048, 4096) f32

    const int rows   = out_size / kH;              // B*S = 16384
    const int blocks = rows / 2;                   // 8192
    fused_gate_copy<<<blocks, 256, 0, stream>>>(x, gate_w, gate_b, pool, lidx, out);
}